// Round 8
// baseline (199.922 us; speedup 1.0000x reference)
//
#include <hip/hip_runtime.h>

#define N_NODES 50000
#define N_EDGES 800000
#define D 128

typedef __attribute__((ext_vector_type(8))) short bf16x8;
typedef __attribute__((ext_vector_type(4))) float f32x4;

__device__ __forceinline__ unsigned short f2bf(float f) {
  unsigned u = __float_as_uint(f);
  u = (u + 0x7FFFu + ((u >> 16) & 1u)) >> 16;  // RNE
  return (unsigned short)u;
}

// ---------------------------------------------------------------------------
// K1 (fused): feat fp32->bf16 cvt + chain build (unbucketed; bucketing
// measured as zero-effect in round 7). next[e] write is coalesced.
// ---------------------------------------------------------------------------
__global__ void prep_kernel(const float* __restrict__ feat,
                            unsigned short* __restrict__ fb,
                            const int* __restrict__ src,
                            const int* __restrict__ dst,
                            int* __restrict__ head,
                            int* __restrict__ next) {
  int i = blockIdx.x * blockDim.x + threadIdx.x;  // exactly 800000 threads
  float4 a = ((const float4*)feat)[2 * i];
  float4 b = ((const float4*)feat)[2 * i + 1];
  union { unsigned short s[8]; uint4 u; } p;
  p.s[0] = f2bf(a.x); p.s[1] = f2bf(a.y); p.s[2] = f2bf(a.z); p.s[3] = f2bf(a.w);
  p.s[4] = f2bf(b.x); p.s[5] = f2bf(b.y); p.s[6] = f2bf(b.z); p.s[7] = f2bf(b.w);
  ((uint4*)fb)[i] = p.u;
  int d = dst[i];
  int old = atomicExch(&head[d], i);
  next[i] = old;
}

// ---------------------------------------------------------------------------
// W prepack into MFMA-fragment-contiguous layout:
// wtp[((ct*8+ks)*64 + l)*8 + j] = bf16(Wcat[k][n]),
//   n = ct*16 + (l&15), k = ks*32 + (l>>4)*8 + j,  Wcat = [Ws; Wn].
// Each (ct,ks) fragment is a contiguous 1KB block -> the GEMM's B-load is a
// perfectly coalesced 16B/lane global load (L2-resident, 64KB total).
// ---------------------------------------------------------------------------
__global__ void prepack_w_kernel(const float* __restrict__ Ws,
                                 const float* __restrict__ Wn,
                                 unsigned short* __restrict__ wtp) {
  int t = blockIdx.x * blockDim.x + threadIdx.x;  // 32768
  int j = t & 7;
  int l = (t >> 3) & 63;
  int fragid = t >> 9;
  int ks = fragid & 7, ct = fragid >> 3;
  int n = ct * 16 + (l & 15);
  int k = ks * 32 + (l >> 4) * 8 + j;
  float v = (k < 128) ? Ws[k * 128 + n] : Wn[(k - 128) * 128 + n];
  wtp[t] = f2bf(v);
}

// ---------------------------------------------------------------------------
// K2: chain-walk gather-mean; 16 lanes/node, 16B/lane.
// Writes h (fp32) into d_out (consumed in-place by the GEMM).
// ---------------------------------------------------------------------------
__global__ __launch_bounds__(256) void aggregate_chain_bf_kernel(
    const unsigned short* __restrict__ fb, const int* __restrict__ head,
    const int* __restrict__ next, const int* __restrict__ src,
    float* __restrict__ h) {
  int g = (blockIdx.x * blockDim.x + threadIdx.x) >> 4;
  int lane = threadIdx.x & 15;
  if (g >= N_NODES) return;
  const unsigned short* fl = fb + lane * 8;
  float acc[8] = {0.f, 0.f, 0.f, 0.f, 0.f, 0.f, 0.f, 0.f};
  int cnt = 0;
  int e = head[g];
  while (e >= 0) {
    int s = src[e];
    int en = next[e];  // independent of the gather; issues alongside
    uint4 v = *(const uint4*)(fl + (size_t)s * D);
    acc[0] += __uint_as_float(v.x << 16);
    acc[1] += __uint_as_float(v.x & 0xFFFF0000u);
    acc[2] += __uint_as_float(v.y << 16);
    acc[3] += __uint_as_float(v.y & 0xFFFF0000u);
    acc[4] += __uint_as_float(v.z << 16);
    acc[5] += __uint_as_float(v.z & 0xFFFF0000u);
    acc[6] += __uint_as_float(v.w << 16);
    acc[7] += __uint_as_float(v.w & 0xFFFF0000u);
    ++cnt;
    e = en;
  }
  float scale = (cnt > 0) ? (1.0f / (float)cnt) : 0.0f;
  float* op = h + (size_t)g * D + lane * 8;
  float4 o0 = {acc[0] * scale, acc[1] * scale, acc[2] * scale, acc[3] * scale};
  float4 o1 = {acc[4] * scale, acc[5] * scale, acc[6] * scale, acc[7] * scale};
  *(float4*)op = o0;
  *(float4*)(op + 4) = o1;
}

// ---------------------------------------------------------------------------
// K3: LDS-free MFMA GEMM: out = [fb | bf16(h)] @ Wcat + bias.
// h read in-place from out. 256 thr = 4 waves x 16 rows = 64 rows/block,
// 782 blocks (~3/CU). B-frags are coalesced global loads from wtp (L2-hit).
// In-place safety: a block reads h ONLY for its own 64 rows, all before the
// single barrier; all out writes after it. No LDS -> no 2-block/CU cap.
// ---------------------------------------------------------------------------
__global__ __launch_bounds__(256) void gemm_mfma2_kernel(
    const unsigned short* __restrict__ fb, const unsigned short* __restrict__ wtp,
    const float* __restrict__ bias, float* out) {
  const int tid = threadIdx.x;
  const int w = tid >> 6;
  const int l = tid & 63;
  const int li = l & 15;
  const int lg = l >> 4;
  const int koff = lg * 8;
  const int row0 = blockIdx.x * 64 + w * 16;
  int arow = row0 + li;
  if (arow > N_NODES - 1) arow = N_NODES - 1;  // clamp; results discarded

  // A-frags: feat half (bf16 direct)
  bf16x8 afrag[8];
  const unsigned short* fbp = fb + (size_t)arow * D + koff;
#pragma unroll
  for (int ks = 0; ks < 4; ++ks)
    afrag[ks] = *(const bf16x8*)(fbp + ks * 32);
  // A-frags: h half (fp32 in-place from out)
  const float* hp = out + (size_t)arow * D + koff;
  float4 h0[4], h1[4];
#pragma unroll
  for (int ks = 0; ks < 4; ++ks) {
    h0[ks] = *(const float4*)(hp + ks * 32);
    h1[ks] = *(const float4*)(hp + ks * 32 + 4);
  }
#pragma unroll
  for (int ks = 0; ks < 4; ++ks) {
    bf16x8 a;
    a[0] = (short)f2bf(h0[ks].x); a[1] = (short)f2bf(h0[ks].y);
    a[2] = (short)f2bf(h0[ks].z); a[3] = (short)f2bf(h0[ks].w);
    a[4] = (short)f2bf(h1[ks].x); a[5] = (short)f2bf(h1[ks].y);
    a[6] = (short)f2bf(h1[ks].z); a[7] = (short)f2bf(h1[ks].w);
    afrag[4 + ks] = a;
  }
  __syncthreads();  // all in-place h reads of this block's rows done

  f32x4 acc[8];
  const f32x4 zero = {0.f, 0.f, 0.f, 0.f};
#pragma unroll
  for (int ct = 0; ct < 8; ++ct) acc[ct] = zero;

#pragma unroll
  for (int ks = 0; ks < 8; ++ks) {
#pragma unroll
    for (int ct = 0; ct < 8; ++ct) {
      bf16x8 b = *(const bf16x8*)(wtp + (((ct << 3) + ks) << 9) + l * 8);
      acc[ct] = __builtin_amdgcn_mfma_f32_16x16x32_bf16(afrag[ks], b, acc[ct], 0, 0, 0);
    }
  }

  // epilogue: D elem (row=(l>>4)*4+j, col=l&15) per 16-col tile
#pragma unroll
  for (int ct = 0; ct < 8; ++ct) {
    int c = ct * 16 + li;
    float bv = bias[c];
#pragma unroll
    for (int j = 0; j < 4; ++j) {
      int row = row0 + lg * 4 + j;
      if (row < N_NODES) out[(size_t)row * D + c] = acc[ct][j] + bv;
    }
  }
}

// ---------------------------------------------------------------------------
// Fallback fp32 path (only if ws_size < ~16.3 MB): chain aggregate on fp32
// feat + in-place fp32 GEMM. Needs only head+next (3.4 MB).
// ---------------------------------------------------------------------------
__global__ void build_chain_f32_kernel(const int* __restrict__ src,
                                       const int* __restrict__ dst,
                                       int* __restrict__ head,
                                       int* __restrict__ next) {
  int e = blockIdx.x * blockDim.x + threadIdx.x;
  if (e < N_EDGES) {
    int d = dst[e];
    int old = atomicExch(&head[d], e);
    next[e] = old;
  }
}

__global__ __launch_bounds__(256) void aggregate_chain_f32_kernel(
    const float* __restrict__ feat, const int* __restrict__ head,
    const int* __restrict__ next, const int* __restrict__ src,
    float* __restrict__ h) {
  int g = (blockIdx.x * blockDim.x + threadIdx.x) >> 5;
  int lane = threadIdx.x & 31;
  if (g >= N_NODES) return;
  float4 acc = {0.f, 0.f, 0.f, 0.f};
  int cnt = 0;
  int e = head[g];
  while (e >= 0) {
    int s = src[e];
    int en = next[e];
    float4 f = *reinterpret_cast<const float4*>(feat + (size_t)s * D + lane * 4);
    acc.x += f.x; acc.y += f.y; acc.z += f.z; acc.w += f.w;
    ++cnt;
    e = en;
  }
  float scale = (cnt > 0) ? (1.0f / (float)cnt) : 0.0f;
  float4 o = {acc.x * scale, acc.y * scale, acc.z * scale, acc.w * scale};
  *reinterpret_cast<float4*>(h + (size_t)g * D + lane * 4) = o;
}

__global__ __launch_bounds__(256) void gemm_f32_kernel(
    const float* __restrict__ feat, const float* __restrict__ Ws,
    const float* __restrict__ Wn, const float* __restrict__ bias,
    float* __restrict__ out) {
  __shared__ float f_lds[64][132];
  __shared__ float h_lds[64][132];
  const int tid = threadIdx.x;
  const int r0 = blockIdx.x * 64;
  {
    int row = tid >> 2;
    int c0 = (tid & 3) * 32;
    int r = r0 + row;
    if (r < N_NODES) {
      const float* fs = feat + (size_t)r * D + c0;
      const float* hs = out + (size_t)r * D + c0;
#pragma unroll
      for (int j = 0; j < 8; ++j) {
        float4 a = *reinterpret_cast<const float4*>(fs + j * 4);
        float4 b = *reinterpret_cast<const float4*>(hs + j * 4);
        *reinterpret_cast<float4*>(&f_lds[row][c0 + j * 4]) = a;
        *reinterpret_cast<float4*>(&h_lds[row][c0 + j * 4]) = b;
      }
    } else {
      float4 z = {0.f, 0.f, 0.f, 0.f};
#pragma unroll
      for (int j = 0; j < 8; ++j) {
        *reinterpret_cast<float4*>(&f_lds[row][c0 + j * 4]) = z;
        *reinterpret_cast<float4*>(&h_lds[row][c0 + j * 4]) = z;
      }
    }
  }
  __syncthreads();
  const int rs = tid & 15;
  const int n = (tid >> 4) * 8;
  float acc[4][8];
#pragma unroll
  for (int m = 0; m < 4; ++m)
#pragma unroll
    for (int j = 0; j < 8; ++j) acc[m][j] = 0.f;
#pragma unroll 4
  for (int k = 0; k < D; ++k) {
    float4 w0 = *reinterpret_cast<const float4*>(Ws + k * D + n);
    float4 w1 = *reinterpret_cast<const float4*>(Ws + k * D + n + 4);
    float4 v0 = *reinterpret_cast<const float4*>(Wn + k * D + n);
    float4 v1 = *reinterpret_cast<const float4*>(Wn + k * D + n + 4);
#pragma unroll
    for (int m = 0; m < 4; ++m) {
      float xf = f_lds[rs + m * 16][k];
      float xh = h_lds[rs + m * 16][k];
      acc[m][0] = fmaf(xf, w0.x, fmaf(xh, v0.x, acc[m][0]));
      acc[m][1] = fmaf(xf, w0.y, fmaf(xh, v0.y, acc[m][1]));
      acc[m][2] = fmaf(xf, w0.z, fmaf(xh, v0.z, acc[m][2]));
      acc[m][3] = fmaf(xf, w0.w, fmaf(xh, v0.w, acc[m][3]));
      acc[m][4] = fmaf(xf, w1.x, fmaf(xh, v1.x, acc[m][4]));
      acc[m][5] = fmaf(xf, w1.y, fmaf(xh, v1.y, acc[m][5]));
      acc[m][6] = fmaf(xf, w1.z, fmaf(xh, v1.z, acc[m][6]));
      acc[m][7] = fmaf(xf, w1.w, fmaf(xh, v1.w, acc[m][7]));
    }
  }
  float4 b0 = *reinterpret_cast<const float4*>(bias + n);
  float4 b1 = *reinterpret_cast<const float4*>(bias + n + 4);
#pragma unroll
  for (int m = 0; m < 4; ++m) {
    int r = r0 + rs + m * 16;
    if (r < N_NODES) {
      float4 o0 = {acc[m][0] + b0.x, acc[m][1] + b0.y, acc[m][2] + b0.z, acc[m][3] + b0.w};
      float4 o1 = {acc[m][4] + b1.x, acc[m][5] + b1.y, acc[m][6] + b1.z, acc[m][7] + b1.w};
      *reinterpret_cast<float4*>(out + (size_t)r * D + n) = o0;
      *reinterpret_cast<float4*>(out + (size_t)r * D + n + 4) = o1;
    }
  }
}

// ---------------------------------------------------------------------------
extern "C" void kernel_launch(void* const* d_in, const int* in_sizes, int n_in,
                              void* d_out, int out_size, void* d_ws, size_t ws_size,
                              hipStream_t stream) {
  const float* feat = (const float*)d_in[0];
  const int* src    = (const int*)d_in[1];
  const int* dst    = (const int*)d_in[2];
  const float* Ws   = (const float*)d_in[3];
  const float* Wn   = (const float*)d_in[4];
  const float* bias = (const float*)d_in[5];
  float* out = (float*)d_out;

  // workspace layout (~16.3 MB full path)
  int* head = (int*)d_ws;                          // 50176 (padded)
  int* next = head + 50176;                        // N_EDGES
  unsigned short* fb  = (unsigned short*)(next + N_EDGES);  // 6.4M bf16
  unsigned short* wtp = fb + (size_t)N_NODES * D;           // 32768 bf16
  size_t need_full = (size_t)((char*)(wtp + 32768) - (char*)d_ws);
  size_t need_min  = (size_t)((char*)(next + N_EDGES) - (char*)d_ws);

  hipMemsetAsync(head, 0xFF, 50176 * sizeof(int), stream);  // head[] = -1

  if (ws_size >= need_full) {
    prep_kernel<<<3125, 256, 0, stream>>>(feat, fb, src, dst, head, next);
    prepack_w_kernel<<<128, 256, 0, stream>>>(Ws, Wn, wtp);
    aggregate_chain_bf_kernel<<<3125, 256, 0, stream>>>(fb, head, next, src, out);
    gemm_mfma2_kernel<<<782, 256, 0, stream>>>(fb, wtp, bias, out);
  } else if (ws_size >= need_min) {
    build_chain_f32_kernel<<<3125, 256, 0, stream>>>(src, dst, head, next);
    aggregate_chain_f32_kernel<<<6250, 256, 0, stream>>>(feat, head, next, src, out);
    gemm_f32_kernel<<<(N_NODES + 63) / 64, 256, 0, stream>>>(feat, Ws, Wn, bias, out);
  }
}

// Round 9
// 183.467 us; speedup vs baseline: 1.0897x; 1.0897x over previous
//
#include <hip/hip_runtime.h>

#define N_NODES 50000
#define N_EDGES 800000
#define D 128

typedef __attribute__((ext_vector_type(8))) short bf16x8;
typedef __attribute__((ext_vector_type(4))) float f32x4;

__device__ __forceinline__ unsigned short f2bf(float f) {
  unsigned u = __float_as_uint(f);
  u = (u + 0x7FFFu + ((u >> 16) & 1u)) >> 16;  // RNE
  return (unsigned short)u;
}

// ---------------------------------------------------------------------------
// K1 (fused): feat fp32->bf16 cvt + chain build (unbucketed).
// ---------------------------------------------------------------------------
__global__ void prep_kernel(const float* __restrict__ feat,
                            unsigned short* __restrict__ fb,
                            const int* __restrict__ src,
                            const int* __restrict__ dst,
                            int* __restrict__ head,
                            int* __restrict__ next) {
  int i = blockIdx.x * blockDim.x + threadIdx.x;  // exactly 800000 threads
  float4 a = ((const float4*)feat)[2 * i];
  float4 b = ((const float4*)feat)[2 * i + 1];
  union { unsigned short s[8]; uint4 u; } p;
  p.s[0] = f2bf(a.x); p.s[1] = f2bf(a.y); p.s[2] = f2bf(a.z); p.s[3] = f2bf(a.w);
  p.s[4] = f2bf(b.x); p.s[5] = f2bf(b.y); p.s[6] = f2bf(b.z); p.s[7] = f2bf(b.w);
  ((uint4*)fb)[i] = p.u;
  int d = dst[i];
  int old = atomicExch(&head[d], i);
  next[i] = old;
}

// ---------------------------------------------------------------------------
// W prepack (round-7 layout): wt[n*256 + k] = bf16(Wcat[k][n])
// ---------------------------------------------------------------------------
__global__ void prepack_w_kernel(const float* __restrict__ Ws,
                                 const float* __restrict__ Wn,
                                 unsigned short* __restrict__ wt) {
  int t = blockIdx.x * blockDim.x + threadIdx.x;  // 32768
  int n = t >> 8, k = t & 255;
  float v = (k < 128) ? Ws[k * 128 + n] : Wn[(k - 128) * 128 + n];
  wt[t] = f2bf(v);
}

// ---------------------------------------------------------------------------
// K2: chain-walk gather-mean; 16 lanes/node, 16B/lane.
// HB16=1: write h as bf16 into hb (full path).  HB16=0: fp32 into out (mid).
// ---------------------------------------------------------------------------
template <int HB16>
__global__ __launch_bounds__(256) void aggregate_chain_bf_kernel(
    const unsigned short* __restrict__ fb, const int* __restrict__ head,
    const int* __restrict__ next, const int* __restrict__ src,
    float* __restrict__ h, unsigned short* __restrict__ hb) {
  int g = (blockIdx.x * blockDim.x + threadIdx.x) >> 4;
  int lane = threadIdx.x & 15;
  if (g >= N_NODES) return;
  const unsigned short* fl = fb + lane * 8;
  float acc[8] = {0.f, 0.f, 0.f, 0.f, 0.f, 0.f, 0.f, 0.f};
  int cnt = 0;
  int e = head[g];
  while (e >= 0) {
    int s = src[e];
    int en = next[e];  // independent of the gather; issues alongside
    uint4 v = *(const uint4*)(fl + (size_t)s * D);
    acc[0] += __uint_as_float(v.x << 16);
    acc[1] += __uint_as_float(v.x & 0xFFFF0000u);
    acc[2] += __uint_as_float(v.y << 16);
    acc[3] += __uint_as_float(v.y & 0xFFFF0000u);
    acc[4] += __uint_as_float(v.z << 16);
    acc[5] += __uint_as_float(v.z & 0xFFFF0000u);
    acc[6] += __uint_as_float(v.w << 16);
    acc[7] += __uint_as_float(v.w & 0xFFFF0000u);
    ++cnt;
    e = en;
  }
  float scale = (cnt > 0) ? (1.0f / (float)cnt) : 0.0f;
  if (HB16) {
    union { unsigned short s[8]; uint4 u; } p;
#pragma unroll
    for (int j = 0; j < 8; ++j) p.s[j] = f2bf(acc[j] * scale);
    *(uint4*)(hb + (size_t)g * D + lane * 8) = p.u;
  } else {
    float* op = h + (size_t)g * D + lane * 8;
    float4 o0 = {acc[0] * scale, acc[1] * scale, acc[2] * scale, acc[3] * scale};
    float4 o1 = {acc[4] * scale, acc[5] * scale, acc[6] * scale, acc[7] * scale};
    *(float4*)op = o0;
    *(float4*)(op + 4) = o1;
  }
}

// ---------------------------------------------------------------------------
// K3: MFMA GEMM (round-7 LDS-staged structure): out = [fb | h] @ Wcat + bias.
// HB16=1: h read as bf16 from hb.  HB16=0: h fp32 in-place from out
// (all in-place reads before the single barrier; writes after).
// 512 thr = 8 waves x 16 rows = 128 rows/block. Wt (n-major, pad 264) in LDS.
// ---------------------------------------------------------------------------
template <int HB16>
__global__ __launch_bounds__(512) void gemm_mfma_kernel(
    const unsigned short* __restrict__ fb, const unsigned short* __restrict__ hb,
    const unsigned short* __restrict__ wt, const float* __restrict__ bias,
    float* out) {
  __shared__ unsigned short wt_lds[128 * 264];  // 67584 B
  const int tid = threadIdx.x;
  const int w = tid >> 6;
  const int l = tid & 63;
  const int li = l & 15;
  const int lg = l >> 4;
  const int koff = lg * 8;
  const int r0 = blockIdx.x * 128 + w * 16;
  int arow = r0 + li;
  if (arow > N_NODES - 1) arow = N_NODES - 1;  // clamp; results discarded

  // A prefetch: feat half (bf16 direct)
  bf16x8 afrag[8];
  const unsigned short* fbp = fb + (size_t)arow * D + koff;
#pragma unroll
  for (int ks = 0; ks < 4; ++ks)
    afrag[ks] = *(const bf16x8*)(fbp + ks * 32);

  float4 h0[4], h1[4];
  if (HB16) {
    // h half directly as bf16
    const unsigned short* hp = hb + (size_t)arow * D + koff;
#pragma unroll
    for (int ks = 0; ks < 4; ++ks)
      afrag[4 + ks] = *(const bf16x8*)(hp + ks * 32);
  } else {
    const float* hp = out + (size_t)arow * D + koff;
#pragma unroll
    for (int ks = 0; ks < 4; ++ks) {
      h0[ks] = *(const float4*)(hp + ks * 32);
      h1[ks] = *(const float4*)(hp + ks * 32 + 4);
    }
  }

  // stage Wt into LDS (padded rows: 264 bf16 -> balanced banks)
#pragma unroll
  for (int i = 0; i < 8; ++i) {
    int idx = tid + i * 512;  // 0..4095 chunks of 16B
    int row = idx >> 5, seg = idx & 31;
    uint4 v = *(const uint4*)(wt + row * 256 + seg * 8);
    *(uint4*)(&wt_lds[row * 264 + seg * 8]) = v;
  }

  if (!HB16) {
#pragma unroll
    for (int ks = 0; ks < 4; ++ks) {
      bf16x8 a;
      a[0] = (short)f2bf(h0[ks].x); a[1] = (short)f2bf(h0[ks].y);
      a[2] = (short)f2bf(h0[ks].z); a[3] = (short)f2bf(h0[ks].w);
      a[4] = (short)f2bf(h1[ks].x); a[5] = (short)f2bf(h1[ks].y);
      a[6] = (short)f2bf(h1[ks].z); a[7] = (short)f2bf(h1[ks].w);
      afrag[4 + ks] = a;
    }
  }
  __syncthreads();

  f32x4 acc[8];
  const f32x4 zero = {0.f, 0.f, 0.f, 0.f};
#pragma unroll
  for (int ct = 0; ct < 8; ++ct) acc[ct] = zero;

#pragma unroll
  for (int ks = 0; ks < 8; ++ks) {
#pragma unroll
    for (int ct = 0; ct < 8; ++ct) {
      bf16x8 b = *(const bf16x8*)(&wt_lds[(ct * 16 + li) * 264 + ks * 32 + koff]);
      acc[ct] = __builtin_amdgcn_mfma_f32_16x16x32_bf16(afrag[ks], b, acc[ct], 0, 0, 0);
    }
  }

  // epilogue: D elem (row=(l>>4)*4+j, col=l&15) per 16-col tile
#pragma unroll
  for (int ct = 0; ct < 8; ++ct) {
    int c = ct * 16 + li;
    float bv = bias[c];
#pragma unroll
    for (int j = 0; j < 4; ++j) {
      int row = r0 + lg * 4 + j;
      if (row < N_NODES) out[(size_t)row * D + c] = acc[ct][j] + bv;
    }
  }
}

// ---------------------------------------------------------------------------
// Fallback fp32 path (ws too small for bf16 buffers): chain aggregate on
// fp32 feat + in-place fp32 GEMM. Needs only head+next (3.4 MB).
// ---------------------------------------------------------------------------
__global__ void build_chain_f32_kernel(const int* __restrict__ src,
                                       const int* __restrict__ dst,
                                       int* __restrict__ head,
                                       int* __restrict__ next) {
  int e = blockIdx.x * blockDim.x + threadIdx.x;
  if (e < N_EDGES) {
    int d = dst[e];
    int old = atomicExch(&head[d], e);
    next[e] = old;
  }
}

__global__ __launch_bounds__(256) void aggregate_chain_f32_kernel(
    const float* __restrict__ feat, const int* __restrict__ head,
    const int* __restrict__ next, const int* __restrict__ src,
    float* __restrict__ h) {
  int g = (blockIdx.x * blockDim.x + threadIdx.x) >> 5;
  int lane = threadIdx.x & 31;
  if (g >= N_NODES) return;
  float4 acc = {0.f, 0.f, 0.f, 0.f};
  int cnt = 0;
  int e = head[g];
  while (e >= 0) {
    int s = src[e];
    int en = next[e];
    float4 f = *reinterpret_cast<const float4*>(feat + (size_t)s * D + lane * 4);
    acc.x += f.x; acc.y += f.y; acc.z += f.z; acc.w += f.w;
    ++cnt;
    e = en;
  }
  float scale = (cnt > 0) ? (1.0f / (float)cnt) : 0.0f;
  float4 o = {acc.x * scale, acc.y * scale, acc.z * scale, acc.w * scale};
  *reinterpret_cast<float4*>(h + (size_t)g * D + lane * 4) = o;
}

__global__ __launch_bounds__(256) void gemm_f32_kernel(
    const float* __restrict__ feat, const float* __restrict__ Ws,
    const float* __restrict__ Wn, const float* __restrict__ bias,
    float* __restrict__ out) {
  __shared__ float f_lds[64][132];
  __shared__ float h_lds[64][132];
  const int tid = threadIdx.x;
  const int r0 = blockIdx.x * 64;
  {
    int row = tid >> 2;
    int c0 = (tid & 3) * 32;
    int r = r0 + row;
    if (r < N_NODES) {
      const float* fs = feat + (size_t)r * D + c0;
      const float* hs = out + (size_t)r * D + c0;
#pragma unroll
      for (int j = 0; j < 8; ++j) {
        float4 a = *reinterpret_cast<const float4*>(fs + j * 4);
        float4 b = *reinterpret_cast<const float4*>(hs + j * 4);
        *reinterpret_cast<float4*>(&f_lds[row][c0 + j * 4]) = a;
        *reinterpret_cast<float4*>(&h_lds[row][c0 + j * 4]) = b;
      }
    } else {
      float4 z = {0.f, 0.f, 0.f, 0.f};
#pragma unroll
      for (int j = 0; j < 8; ++j) {
        *reinterpret_cast<float4*>(&f_lds[row][c0 + j * 4]) = z;
        *reinterpret_cast<float4*>(&h_lds[row][c0 + j * 4]) = z;
      }
    }
  }
  __syncthreads();
  const int rs = tid & 15;
  const int n = (tid >> 4) * 8;
  float acc[4][8];
#pragma unroll
  for (int m = 0; m < 4; ++m)
#pragma unroll
    for (int j = 0; j < 8; ++j) acc[m][j] = 0.f;
#pragma unroll 4
  for (int k = 0; k < D; ++k) {
    float4 w0 = *reinterpret_cast<const float4*>(Ws + k * D + n);
    float4 w1 = *reinterpret_cast<const float4*>(Ws + k * D + n + 4);
    float4 v0 = *reinterpret_cast<const float4*>(Wn + k * D + n);
    float4 v1 = *reinterpret_cast<const float4*>(Wn + k * D + n + 4);
#pragma unroll
    for (int m = 0; m < 4; ++m) {
      float xf = f_lds[rs + m * 16][k];
      float xh = h_lds[rs + m * 16][k];
      acc[m][0] = fmaf(xf, w0.x, fmaf(xh, v0.x, acc[m][0]));
      acc[m][1] = fmaf(xf, w0.y, fmaf(xh, v0.y, acc[m][1]));
      acc[m][2] = fmaf(xf, w0.z, fmaf(xh, v0.z, acc[m][2]));
      acc[m][3] = fmaf(xf, w0.w, fmaf(xh, v0.w, acc[m][3]));
      acc[m][4] = fmaf(xf, w1.x, fmaf(xh, v1.x, acc[m][4]));
      acc[m][5] = fmaf(xf, w1.y, fmaf(xh, v1.y, acc[m][5]));
      acc[m][6] = fmaf(xf, w1.z, fmaf(xh, v1.z, acc[m][6]));
      acc[m][7] = fmaf(xf, w1.w, fmaf(xh, v1.w, acc[m][7]));
    }
  }
  float4 b0 = *reinterpret_cast<const float4*>(bias + n);
  float4 b1 = *reinterpret_cast<const float4*>(bias + n + 4);
#pragma unroll
  for (int m = 0; m < 4; ++m) {
    int r = r0 + rs + m * 16;
    if (r < N_NODES) {
      float4 o0 = {acc[m][0] + b0.x, acc[m][1] + b0.y, acc[m][2] + b0.z, acc[m][3] + b0.w};
      float4 o1 = {acc[m][4] + b1.x, acc[m][5] + b1.y, acc[m][6] + b1.z, acc[m][7] + b1.w};
      *reinterpret_cast<float4*>(out + (size_t)r * D + n) = o0;
      *reinterpret_cast<float4*>(out + (size_t)r * D + n + 4) = o1;
    }
  }
}

// ---------------------------------------------------------------------------
extern "C" void kernel_launch(void* const* d_in, const int* in_sizes, int n_in,
                              void* d_out, int out_size, void* d_ws, size_t ws_size,
                              hipStream_t stream) {
  const float* feat = (const float*)d_in[0];
  const int* src    = (const int*)d_in[1];
  const int* dst    = (const int*)d_in[2];
  const float* Ws   = (const float*)d_in[3];
  const float* Wn   = (const float*)d_in[4];
  const float* bias = (const float*)d_in[5];
  float* out = (float*)d_out;

  // workspace layout
  int* head = (int*)d_ws;                                    // 50176 (padded)
  int* next = head + 50176;                                  // N_EDGES
  unsigned short* fb = (unsigned short*)(next + N_EDGES);    // 6.4M bf16
  unsigned short* wt = fb + (size_t)N_NODES * D;             // 32768 bf16
  unsigned short* hb = wt + 32768;                           // 6.4M bf16 (full only)
  size_t need_full = (size_t)((char*)(hb + (size_t)N_NODES * D) - (char*)d_ws); // ~29.1 MB
  size_t need_mid  = (size_t)((char*)(wt + 32768) - (char*)d_ws);               // ~16.3 MB
  size_t need_min  = (size_t)((char*)(next + N_EDGES) - (char*)d_ws);           // ~3.4 MB

  hipMemsetAsync(head, 0xFF, 50176 * sizeof(int), stream);  // head[] = -1

  if (ws_size >= need_full) {
    prep_kernel<<<3125, 256, 0, stream>>>(feat, fb, src, dst, head, next);
    prepack_w_kernel<<<128, 256, 0, stream>>>(Ws, Wn, wt);
    aggregate_chain_bf_kernel<1><<<3125, 256, 0, stream>>>(fb, head, next, src, nullptr, hb);
    gemm_mfma_kernel<1><<<391, 512, 0, stream>>>(fb, hb, wt, bias, out);
  } else if (ws_size >= need_mid) {
    prep_kernel<<<3125, 256, 0, stream>>>(feat, fb, src, dst, head, next);
    prepack_w_kernel<<<128, 256, 0, stream>>>(Ws, Wn, wt);
    aggregate_chain_bf_kernel<0><<<3125, 256, 0, stream>>>(fb, head, next, src, out, nullptr);
    gemm_mfma_kernel<0><<<391, 512, 0, stream>>>(fb, nullptr, wt, bias, out);
  } else if (ws_size >= need_min) {
    build_chain_f32_kernel<<<3125, 256, 0, stream>>>(src, dst, head, next);
    aggregate_chain_f32_kernel<<<6250, 256, 0, stream>>>(feat, head, next, src, out);
    gemm_f32_kernel<<<(N_NODES + 63) / 64, 256, 0, stream>>>(feat, Ws, Wn, bias, out);
  }
}